// Round 2
// baseline (731.730 us; speedup 1.0000x reference)
//
#include <hip/hip_runtime.h>
#include <hip/hip_bf16.h>
#include <stdint.h>

#define F 128
#define R 6
#define NTYPES 95
#define MTILE 128
#define HPAD 136   // shorts per h_bf row (272 B, 16B-aligned, breaks b128 bank aliasing)
#define SPAD 132   // floats per stage row (+4 pad)

typedef short bf16x8 __attribute__((ext_vector_type(8)));
typedef float floatx4 __attribute__((ext_vector_type(4)));

__device__ __forceinline__ unsigned short f2bf(float x) {
    union { float f; unsigned u; } cv; cv.f = x;
    unsigned u = cv.u;
    return (unsigned short)((u + 0x7FFFu + ((u >> 16) & 1u)) >> 16);  // RNE
}

__device__ __forceinline__ float swishf(float x) {
    return x * __builtin_amdgcn_rcpf(1.0f + __expf(-x));
}

// blocks 0..94: embW[z][0:128] = emb[z]@W[0:128] + b (bias folded), embW[z][128:256] = emb[z]@W[128:256]
// blocks 95..158: w2t[n][k] = bf16(W[256+k][n])  (K-contiguous rows for MFMA B-frags)
__global__ void prep_kernel(const float* __restrict__ emb,
                            const float* __restrict__ W,
                            const float* __restrict__ bvec,
                            float* __restrict__ embW,
                            unsigned short* __restrict__ w2t) {
    int t = threadIdx.x;
    int b = blockIdx.x;
    if (b < NTYPES) {
        int c = t >> 7, f = t & 127;
        const float* er = emb + b * F;
        const float* Wc = W + c * F * F;
        float a = 0.f;
        #pragma unroll 8
        for (int k = 0; k < F; ++k) a = __builtin_fmaf(er[k], Wc[k * F + f], a);
        if (c == 0) a += bvec[f];
        embW[b * 256 + c * F + f] = a;
    } else {
        int idx = (b - NTYPES) * 256 + t;  // 0..16383
        int n = idx >> 7, k = idx & 127;
        w2t[n * F + k] = f2bf(W[(256 + k) * F + n]);
    }
}

__global__ __launch_bounds__(256) void
edge_kernel(const int* __restrict__ Z,
            const float* __restrict__ rbf,
            const int* __restrict__ idnb_i,
            const int* __restrict__ idnb_j,
            const float* __restrict__ W_rbf,
            const float* __restrict__ b_rbf,
            const float* __restrict__ embW,
            const unsigned short* __restrict__ w2t,
            float* __restrict__ out,
            int E) {
    // h_bf (bf16 A-tile) and the fp32 epilogue stage alias the same LDS
    __shared__ __align__(16) union {
        short h[MTILE * HPAD];   // 34816 B
        float s[64 * SPAD];      // 33792 B
    } shm;
    __shared__ float rbf_s[MTILE * R];
    __shared__ int zi_s[MTILE];
    __shared__ int zj_s[MTILE];

    const int t = threadIdx.x;
    const long ebase = (long)blockIdx.x * MTILE;

    // ---- stage rbf (coalesced) + type gathers ----
    #pragma unroll
    for (int i = 0; i < 3; ++i) {
        int idx = i * 256 + t;
        long g = ebase * R + idx;
        rbf_s[idx] = (g < (long)E * R) ? rbf[g] : 0.f;
    }
    if (t < MTILE) {
        long e = ebase + t;
        long ec = (e < (long)E) ? e : 0;
        zi_s[t] = Z[idnb_i[ec]];
        zj_s[t] = Z[idnb_j[ec]];
    }

    // ---- W_rbf / b_rbf register tiles: thread = (eg, fg) = 8 edges x 8 features ----
    const int fg = t & 15;          // feature group: f0..f0+7
    const int eg = t >> 4;          // edge group:    eg*8..eg*8+7
    const int f0 = fg * 8;
    float wr[R][8], brb[8];
    #pragma unroll
    for (int r = 0; r < R; ++r) {
        floatx4 a = *(const floatx4*)(W_rbf + r * F + f0);
        floatx4 b = *(const floatx4*)(W_rbf + r * F + f0 + 4);
        wr[r][0] = a[0]; wr[r][1] = a[1]; wr[r][2] = a[2]; wr[r][3] = a[3];
        wr[r][4] = b[0]; wr[r][5] = b[1]; wr[r][6] = b[2]; wr[r][7] = b[3];
    }
    {
        floatx4 a = *(const floatx4*)(b_rbf + f0);
        floatx4 b = *(const floatx4*)(b_rbf + f0 + 4);
        brb[0] = a[0]; brb[1] = a[1]; brb[2] = a[2]; brb[3] = a[3];
        brb[4] = b[0]; brb[5] = b[1]; brb[6] = b[2]; brb[7] = b[3];
    }

    __syncthreads();

    // ---- rbf_h tile: swish(rbf @ W_rbf + b_rbf) -> bf16 A-tile ----
    #pragma unroll
    for (int it = 0; it < 8; ++it) {
        int e = eg * 8 + it;
        const float2* rp = (const float2*)(rbf_s + e * R);  // 8B-aligned (e*24 B)
        float2 r01 = rp[0], r23 = rp[1], r45 = rp[2];
        float rv[R] = {r01.x, r01.y, r23.x, r23.y, r45.x, r45.y};
        float v[8];
        #pragma unroll
        for (int f = 0; f < 8; ++f) v[f] = brb[f];
        #pragma unroll
        for (int r = 0; r < R; ++r)
            #pragma unroll
            for (int f = 0; f < 8; ++f)
                v[f] = __builtin_fmaf(rv[r], wr[r][f], v[f]);
        unsigned pk0 = (unsigned)f2bf(swishf(v[0])) | ((unsigned)f2bf(swishf(v[1])) << 16);
        unsigned pk1 = (unsigned)f2bf(swishf(v[2])) | ((unsigned)f2bf(swishf(v[3])) << 16);
        unsigned pk2 = (unsigned)f2bf(swishf(v[4])) | ((unsigned)f2bf(swishf(v[5])) << 16);
        unsigned pk3 = (unsigned)f2bf(swishf(v[6])) | ((unsigned)f2bf(swishf(v[7])) << 16);
        uint4 pk; pk.x = pk0; pk.y = pk1; pk.z = pk2; pk.w = pk3;
        *(uint4*)(&shm.h[e * HPAD + f0]) = pk;   // 16B store, e*272 + fg*16 bytes
    }

    __syncthreads();

    // ---- MFMA: rbf_h[128x128] @ W2[128x128] (16x16x32 bf16) ----
    const int w = t >> 6;
    const int lid = t & 63;
    const int quad = lid >> 4;
    const int l15 = lid & 15;
    const int wbase = w * 32;

    floatx4 acc[2][8];
    #pragma unroll
    for (int rt = 0; rt < 2; ++rt)
        #pragma unroll
        for (int c = 0; c < 8; ++c)
            acc[rt][c] = (floatx4){0.f, 0.f, 0.f, 0.f};

    const bf16x8* w2v = (const bf16x8*)w2t;
    #pragma unroll
    for (int ks = 0; ks < 4; ++ks) {
        bf16x8 a0 = *(const bf16x8*)(&shm.h[(wbase + l15) * HPAD + ks * 32 + quad * 8]);
        bf16x8 a1 = *(const bf16x8*)(&shm.h[(wbase + 16 + l15) * HPAD + ks * 32 + quad * 8]);
        #pragma unroll
        for (int c = 0; c < 8; ++c) {
            bf16x8 bfr = w2v[(c * 16 + l15) * 16 + ks * 4 + quad];
            acc[0][c] = __builtin_amdgcn_mfma_f32_16x16x32_bf16(a0, bfr, acc[0][c], 0, 0, 0);
            acc[1][c] = __builtin_amdgcn_mfma_f32_16x16x32_bf16(a1, bfr, acc[1][c], 0, 0, 0);
        }
    }

    __syncthreads();   // all A-frag LDS reads done before stage overwrites h_bf

    // ---- epilogue: 2 phases x 64 edges, transpose through LDS, vectorized drain ----
    #pragma unroll
    for (int rt = 0; rt < 2; ++rt) {
        const int row_w = w * 16 + quad * 4;   // stage row base for this lane
        #pragma unroll
        for (int c = 0; c < 8; ++c)
            #pragma unroll
            for (int rg = 0; rg < 4; ++rg)
                shm.s[(row_w + rg) * SPAD + c * 16 + l15] = acc[rt][c][rg];
        __syncthreads();

        #pragma unroll
        for (int i = 0; i < 8; ++i) {
            int cid = i * 256 + t;
            int row_s = cid >> 5;            // 0..63
            int c4 = (cid & 31) * 4;         // feature chunk
            int e_loc = (row_s >> 4) * 32 + rt * 16 + (row_s & 15);
            long e_g = ebase + e_loc;
            if (e_g < (long)E) {
                floatx4 v = *(const floatx4*)(&shm.s[row_s * SPAD + c4]);
                floatx4 a = *(const floatx4*)(embW + zi_s[e_loc] * 256 + c4);
                floatx4 b = *(const floatx4*)(embW + zj_s[e_loc] * 256 + F + c4);
                floatx4 o;
                #pragma unroll
                for (int q = 0; q < 4; ++q) o[q] = swishf(v[q] + a[q] + b[q]);
                *(floatx4*)(out + e_g * F + c4) = o;
            }
        }
        if (rt == 0) __syncthreads();
    }
}

extern "C" void kernel_launch(void* const* d_in, const int* in_sizes, int n_in,
                              void* d_out, int out_size, void* d_ws, size_t ws_size,
                              hipStream_t stream) {
    const int*   Z     = (const int*)d_in[0];
    const float* rbf   = (const float*)d_in[1];
    const int*   id_i  = (const int*)d_in[2];
    const int*   id_j  = (const int*)d_in[3];
    const float* emb   = (const float*)d_in[4];
    const float* W_rbf = (const float*)d_in[5];
    const float* b_rbf = (const float*)d_in[6];
    const float* W     = (const float*)d_in[7];
    const float* bvec  = (const float*)d_in[8];
    float* out = (float*)d_out;
    int E = in_sizes[2];

    float* embW = (float*)d_ws;                                   // 95*256*4 = 97280 B
    unsigned short* w2t = (unsigned short*)((char*)d_ws + 97280); // 128*128*2 = 32768 B

    prep_kernel<<<NTYPES + 64, 256, 0, stream>>>(emb, W, bvec, embW, w2t);
    int grid = (E + MTILE - 1) / MTILE;
    edge_kernel<<<grid, 256, 0, stream>>>(Z, rbf, id_i, id_j, W_rbf, b_rbf,
                                          embW, w2t, out, E);
}